// Round 8
// baseline (307.374 us; speedup 1.0000x reference)
//
#include <hip/hip_runtime.h>

// NCC loss: 9x9 box-filtered local cross-correlation, -mean(cc).
// Inputs: y_pred, y_true (32,4,512,512) fp32. Output: scalar fp32.
//
// R8: ZERO-DS design. Theory: all prior variants (LDS staging or shfl
// halos) serialized on the per-CU DS pipe (~50us of ds_bpermute/ds_read
// occupancy shared by 4 SIMDs) -> VALUBusy pinned ~30% in every config.
// Here each lane loads 16 cols [x0-4, x0+12) (4 aligned float4/array;
// halo cols re-loaded by neighbors = L1 hits) and keeps sh[5][8] =
// horizontally-pre-summed vertical running sums:
//   sh[m][j] = sum_{r in [y-4,y+4]} sum_{c in [j-4,j+4]} moment_m[r][c]
// updated per row with += hrow(y+4), -= hrow(y-4). No LDS, no shfl,
// no barriers. Loads issued ~600 VALU-cycles ahead of use.

#define PAD 4
#define EPS 1e-5f

constexpr int B = 32, C = 4, H = 512, W = 512;
constexpr int ROWS = 16;               // rows per wave-task
constexpr int NCHUNK = H / ROWS;       // 32
constexpr int NTASK = B * C * NCHUNK;  // 4096 independent waves
constexpr int TPB = 128;               // 2 independent waves per block
constexpr int WPB = TPB / 64;
constexpr int NBLK = NTASK / WPB;      // 2048
constexpr float INV_N = 1.0f / 81.0f;

struct Row16 {
    float4 i0, i1, i2, i3;  // y_true cols [x0-4, x0+12)
    float4 j0, j1, j2, j3;  // y_pred cols [x0-4, x0+12)
};

__device__ __forceinline__ void loadrow16(const float* __restrict__ I,
                                          const float* __restrict__ J,
                                          int r, int x0, bool okL, bool okR,
                                          Row16& o) {
    const float* pi = I + (size_t)r * W + x0;
    const float* pj = J + (size_t)r * W + x0;
    const float4 z = {0.f, 0.f, 0.f, 0.f};
    o.i0 = okL ? *(const float4*)(pi - 4) : z;   // exec-masked: lane 0 skips
    o.i1 = *(const float4*)(pi);
    o.i2 = *(const float4*)(pi + 4);
    o.i3 = okR ? *(const float4*)(pi + 8) : z;   // lane 63 skips
    o.j0 = okL ? *(const float4*)(pj - 4) : z;
    o.j1 = *(const float4*)(pj);
    o.j2 = *(const float4*)(pj + 4);
    o.j3 = okR ? *(const float4*)(pj + 8) : z;
}

// 9-wide sliding sum of v[0..15] accumulated (+/-) into sh[0..7].
// Output col x0+j uses v[j..j+8] (v[c] = col x0-4+c).
template <int SGN>
__device__ __forceinline__ void slide(float sh[8], const float v[16]) {
    float t = v[0] + v[1] + v[2] + v[3] + v[4] + v[5] + v[6] + v[7] + v[8];
    if (SGN > 0) sh[0] += t; else sh[0] -= t;
#pragma unroll
    for (int j = 1; j < 8; ++j) {
        t += v[j + 8] - v[j - 1];
        if (SGN > 0) sh[j] += t; else sh[j] -= t;
    }
}

template <int SGN>
__device__ __forceinline__ void foldrow(float sh[5][8], const Row16& R) {
    const float fi[16] = {R.i0.x, R.i0.y, R.i0.z, R.i0.w,
                          R.i1.x, R.i1.y, R.i1.z, R.i1.w,
                          R.i2.x, R.i2.y, R.i2.z, R.i2.w,
                          R.i3.x, R.i3.y, R.i3.z, R.i3.w};
    const float fj[16] = {R.j0.x, R.j0.y, R.j0.z, R.j0.w,
                          R.j1.x, R.j1.y, R.j1.z, R.j1.w,
                          R.j2.x, R.j2.y, R.j2.z, R.j2.w,
                          R.j3.x, R.j3.y, R.j3.z, R.j3.w};
    slide<SGN>(sh[0], fi);
    slide<SGN>(sh[1], fj);
    float t[16];
#pragma unroll
    for (int c = 0; c < 16; ++c) t[c] = fi[c] * fi[c];
    slide<SGN>(sh[2], t);
#pragma unroll
    for (int c = 0; c < 16; ++c) t[c] = fj[c] * fj[c];
    slide<SGN>(sh[3], t);
#pragma unroll
    for (int c = 0; c < 16; ++c) t[c] = fi[c] * fj[c];
    slide<SGN>(sh[4], t);
}

__device__ __forceinline__ float cc8(const float sh[5][8]) {
    float acc = 0.0f;
#pragma unroll
    for (int k = 0; k < 8; ++k) {
        const float mi = sh[0][k] * INV_N;
        const float mj = sh[1][k] * INV_N;
        const float vi = sh[2][k] * INV_N - mi * mi;
        const float vj = sh[3][k] * INV_N - mj * mj;
        const float cv = sh[4][k] * INV_N - mi * mj;
        const float den = fmaxf(vi, 0.0f) * fmaxf(vj, 0.0f) + EPS;
        acc += cv * cv * __builtin_amdgcn_rcpf(den);
    }
    return acc;
}

__global__ __launch_bounds__(TPB) void ncc_partial(
        const float* __restrict__ y_pred, const float* __restrict__ y_true,
        float* __restrict__ partial) {
    const int wid = threadIdx.x >> 6;
    const int lane = threadIdx.x & 63;
    // XCD swizzle (bijective: NBLK % 8 == 0): vertical neighbors share L2.
    const int g = (blockIdx.x & 7) * (NBLK / 8) + (blockIdx.x >> 3);
    const int task = g * WPB + wid;
    const int plane = task >> 5;                 // / NCHUNK
    const int v = task & (NCHUNK - 1);
    const size_t base = (size_t)plane * H * W;
    const float* I = y_true + base;  // reference: I = y_true
    const float* J = y_pred + base;  // reference: J = y_pred
    const int x0 = lane * 8;
    const int y0 = v * ROWS;
    const bool okL = (lane != 0);    // col x0-4 in range
    const bool okR = (lane != 63);   // col x0+11 in range

    float sh[5][8];
#pragma unroll
    for (int m = 0; m < 5; ++m)
#pragma unroll
        for (int j = 0; j < 8; ++j) sh[m][j] = 0.0f;

    // Prime rows [y0-4, y0+3] ∩ [0,H)
    for (int r = y0 - PAD; r < y0 + PAD; ++r) {
        if (r < 0) continue;
        Row16 R;
        loadrow16(I, J, r, x0, okL, okR, R);
        foldrow<+1>(sh, R);
    }
    // Preload A = add-row for iter 0 (y0+4 <= 500 < H always).
    Row16 A;
    loadrow16(I, J, y0 + PAD, x0, okL, okR, A);

    float acc = 0.0f;

    for (int yo = 0; yo < ROWS; ++yo) {
        const int y = y0 + yo;

        // 1. issue sub-row load (row y-4), consumed at step 5 (~600cy away)
        const bool vsub = (yo < ROWS - 1) && (y - PAD >= 0);
        Row16 S;
        if (vsub) loadrow16(I, J, y - PAD, x0, okL, okR, S);

        // 2. fold add-row A (loaded a full iteration ago) -> window [y-4,y+4]
        const bool va = (y + PAD < H);
        if (va) foldrow<+1>(sh, A);

        // 3. issue next add-row (row y+5), consumed at step 2 of next iter
        const bool vna = (yo < ROWS - 1) && (y + PAD + 1 < H);
        if (vna) loadrow16(I, J, y + PAD + 1, x0, okL, okR, A);

        // 4. cc over the 8 owned columns
        acc += cc8(sh);

        // 5. fold sub-row -> window becomes [y-3, y+4] for next iter
        if (vsub) foldrow<-1>(sh, S);
    }

    // Per-wave reduction; one partial per task (deterministic slot).
#pragma unroll
    for (int off = 32; off > 0; off >>= 1)
        acc += __shfl_down(acc, off, 64);
    if (lane == 0) partial[task] = acc;
}

__global__ __launch_bounds__(256) void ncc_final(
        const float* __restrict__ partial, float* __restrict__ out) {
    const int t = threadIdx.x;
    float sum = 0.0f;
    for (int i = t; i < NTASK; i += 256) sum += partial[i];
    __shared__ float ws[4];
#pragma unroll
    for (int off = 32; off > 0; off >>= 1)
        sum += __shfl_down(sum, off, 64);
    if ((t & 63) == 0) ws[t >> 6] = sum;
    __syncthreads();
    if (t == 0) {
        const float tot = ws[0] + ws[1] + ws[2] + ws[3];
        out[0] = -tot / (float)((long long)B * C * H * W);
    }
}

extern "C" void kernel_launch(void* const* d_in, const int* in_sizes, int n_in,
                              void* d_out, int out_size, void* d_ws, size_t ws_size,
                              hipStream_t stream) {
    const float* y_pred = (const float*)d_in[0];
    const float* y_true = (const float*)d_in[1];
    float* out = (float*)d_out;
    float* partial = (float*)d_ws;  // NTASK floats = 16 KB

    ncc_partial<<<NBLK, TPB, 0, stream>>>(y_pred, y_true, partial);
    ncc_final<<<1, 256, 0, stream>>>(partial, out);
}

// Round 9
// 103.952 us; speedup vs baseline: 2.9569x; 2.9569x over previous
//
#include <hip/hip_runtime.h>

// NCC loss: 9x9 box-filtered local cross-correlation, -mean(cc).
// Inputs: y_pred, y_true (32,4,512,512) fp32. Output: scalar fp32.
//
// R9: R1 skeleton (best measured: 96.8us; TPB=128, ROWS=32, LDS
// horizontal pass) with per-row costs cut:
//  - 2-row batching: 2 barriers per 2 rows (R1: 2 per row).
//  - "own" 4 cols read from live registers, only L/R neighbor groups
//    from LDS: 15 DS insts/row (R1: 20).
//  - every row load (add rows y+4,y+5; sub rows y-4,y-3) prefetched a
//    full iteration ahead in registers (R1: load->use adjacent).
//  - n^2-form cc: cc = a^2/(vi*vj + eps*81^4), a = 81*wIJ - wI*wJ,
//    vi = max(81*wI2 - wI^2, 0) -- no INV_N muls, rcpf divide.
// R8 falsified the DS-pipe theory (zero-DS was 3x worse); model now:
// VALU-busy time ~45us constant across structures, dur = 45/VALUBusy;
// attack the stall sources (barrier rate + exposed load latency) while
// not raising instruction count.

#define PAD 4

constexpr int B = 32, C = 4, H = 512, W = 512;
constexpr int ROWS = 32;              // output rows per block
constexpr int TPB = 128;              // 2 waves per block
constexpr int CPT = 4;                // 128*4 = 512 = W
constexpr int SLOTS = 528;            // 4 halo + 512 + 4 halo + pad
constexpr int NCHUNK = H / ROWS;      // 16
constexpr int NBLK = B * C * NCHUNK;  // 2048
constexpr float EPS_N4 = 430.46721f;  // 1e-5 * 81^4

struct RowPx { float4 i, j; };

__device__ __forceinline__ void loadpx(const float* __restrict__ I,
                                       const float* __restrict__ J,
                                       int r, int x0, RowPx& o) {
    o.i = *(const float4*)(I + (size_t)r * W + x0);
    o.j = *(const float4*)(J + (size_t)r * W + x0);
}

template <int SGN>
__device__ __forceinline__ void fold4(float s[5][4], const RowPx& R) {
    const float fi[4] = {R.i.x, R.i.y, R.i.z, R.i.w};
    const float fj[4] = {R.j.x, R.j.y, R.j.z, R.j.w};
#pragma unroll
    for (int k = 0; k < 4; ++k) {
        const float a = fi[k], b = fj[k];
        if (SGN > 0) {
            s[0][k] += a;        s[1][k] += b;
            s[2][k] = fmaf(a, a, s[2][k]);
            s[3][k] = fmaf(b, b, s[3][k]);
            s[4][k] = fmaf(a, b, s[4][k]);
        } else {
            s[0][k] -= a;        s[1][k] -= b;
            s[2][k] = fmaf(-a, a, s[2][k]);
            s[3][k] = fmaf(-b, b, s[3][k]);
            s[4][k] = fmaf(-a, b, s[4][k]);
        }
    }
}

// Horizontal 9-window sums + cc for this thread's 4 columns.
// L/R neighbor groups from LDS; own group from live registers s.
__device__ __forceinline__ float hcc(const float (* __restrict__ vb)[SLOTS],
                                     const float s[5][4], int x0) {
    float h[5][4];
#pragma unroll
    for (int ch = 0; ch < 5; ++ch) {
        const float4 L = *(const float4*)&vb[ch][x0];      // cols x0-4..x0-1
        const float4 R = *(const float4*)&vb[ch][x0 + 8];  // cols x0+4..x0+7
        float t = L.x + L.y + L.z + L.w +
                  s[ch][0] + s[ch][1] + s[ch][2] + s[ch][3] + R.x;
        h[ch][0] = t;
        t += R.y - L.x; h[ch][1] = t;
        t += R.z - L.y; h[ch][2] = t;
        t += R.w - L.z; h[ch][3] = t;
    }
    float acc = 0.0f;
#pragma unroll
    for (int k = 0; k < 4; ++k) {
        const float wi = h[0][k], wj = h[1][k];
        const float a  = fmaf(81.0f, h[4][k], -(wi * wj));
        const float vi = fmaxf(fmaf(81.0f, h[2][k], -(wi * wi)), 0.0f);
        const float vj = fmaxf(fmaf(81.0f, h[3][k], -(wj * wj)), 0.0f);
        const float den = fmaf(vi, vj, EPS_N4);
        acc = fmaf(a * a, __builtin_amdgcn_rcpf(den), acc);
    }
    return acc;
}

__global__ __launch_bounds__(TPB) void ncc_partial(
        const float* __restrict__ y_pred, const float* __restrict__ y_true,
        float* __restrict__ partial) {
    __shared__ float vs[2][5][SLOTS];  // 21120 B: row buffers for y, y+1
    __shared__ float wsum[TPB / 64];

    // XCD swizzle (bijective: 2048 % 8 == 0): vertical neighbors share L2.
    const int bid = (blockIdx.x & 7) * (NBLK / 8) + (blockIdx.x >> 3);
    const int chunk = bid % NCHUNK;
    const int plane = bid / NCHUNK;
    const size_t base = (size_t)plane * H * W;
    const float* I = y_true + base;  // reference: I = y_true
    const float* J = y_pred + base;  // reference: J = y_pred

    const int t = threadIdx.x;
    const int x0 = t * CPT;

    // Zero halo slots in both buffers (SAME zero-padding); never rewritten.
    if (t < 2 * PAD) {
        const int sl = (t < PAD) ? t : (512 + t);  // 0..3, 516..519
#pragma unroll
        for (int b = 0; b < 2; ++b)
#pragma unroll
            for (int ch = 0; ch < 5; ++ch) vs[b][ch][sl] = 0.0f;
    }

    const int y0 = chunk * ROWS;

    float s[5][4];
#pragma unroll
    for (int m = 0; m < 5; ++m)
#pragma unroll
        for (int k = 0; k < 4; ++k) s[m][k] = 0.0f;

    // Prime: s = rows [y0-4, y0+3] ∩ [0,H)
    for (int r = y0 - PAD; r < y0 + PAD; ++r) {
        if (r < 0) continue;
        RowPx R;
        loadpx(I, J, r, x0, R);
        fold4<+1>(s, R);
    }

    // Prefetch registers: A=row y+4, A2=y+5, S=y-4, S2=y-3 (for iter 0).
    RowPx A, A2, S, S2, nS2;
    loadpx(I, J, y0 + PAD, x0, A);        // y0+4 <= 484 < H always
    loadpx(I, J, y0 + PAD + 1, x0, A2);   // y0+5 <= 485 < H always
    if (y0 - PAD >= 0) loadpx(I, J, y0 - PAD, x0, S);
    if (y0 - PAD + 1 >= 0) loadpx(I, J, y0 - PAD + 1, x0, S2);

    float acc = 0.0f;

    for (int yo = 0; yo < ROWS; yo += 2) {
        const int y = y0 + yo;
        // entry invariant: s = rows [y-4, y+3] ∩ image;
        // A=row y+4, A2=y+5, S=y-4, S2=y-3 (valid per guards)

        // --- row y ---
        if (y + PAD < H) fold4<+1>(s, A);            // s = win(y)
#pragma unroll
        for (int ch = 0; ch < 5; ++ch)
            *(float4*)&vs[0][ch][x0 + PAD] =
                make_float4(s[ch][0], s[ch][1], s[ch][2], s[ch][3]);
        if (yo + 2 < ROWS && y + 6 < H) loadpx(I, J, y + 6, x0, A);  // A dead

        __syncthreads();                             // writes(buf0) visible
        acc += hcc(vs[0], s, x0);                    // own = live s = win(y)

        // --- row y+1 ---
        if (y + PAD + 1 < H) fold4<+1>(s, A2);
        if (y - PAD >= 0)    fold4<-1>(s, S);        // s = win(y+1)
#pragma unroll
        for (int ch = 0; ch < 5; ++ch)
            *(float4*)&vs[1][ch][x0 + PAD] =
                make_float4(s[ch][0], s[ch][1], s[ch][2], s[ch][3]);
        if (yo + 2 < ROWS) {                         // A2, S dead; S2 live
            if (y + 7 < H)  loadpx(I, J, y + 7, x0, A2);
            if (y - 2 >= 0) loadpx(I, J, y - 2, x0, S);
            if (y - 1 >= 0) loadpx(I, J, y - 1, x0, nS2);
        }

        __syncthreads();                             // writes(buf1) visible,
                                                     // and buf0 reads done
        acc += hcc(vs[1], s, x0);                    // own = live s = win(y+1)

        if (y - PAD + 1 >= 0) fold4<-1>(s, S2);      // s = [y-2, y+5]
        S2 = nS2;                                    // commit prefetch
        // next entry: [y'-4, y'+3] with y' = y+2  ✓
    }

    // Block reduction (deterministic): wave shuffle + LDS
#pragma unroll
    for (int off = 32; off > 0; off >>= 1)
        acc += __shfl_down(acc, off, 64);
    __syncthreads();
    if ((t & 63) == 0) wsum[t >> 6] = acc;
    __syncthreads();
    if (t == 0) partial[bid] = wsum[0] + wsum[1];
}

__global__ __launch_bounds__(256) void ncc_final(
        const float* __restrict__ partial, float* __restrict__ out) {
    const int t = threadIdx.x;
    float sum = 0.0f;
    for (int i = t; i < NBLK; i += 256) sum += partial[i];
    __shared__ float ws[4];
#pragma unroll
    for (int off = 32; off > 0; off >>= 1)
        sum += __shfl_down(sum, off, 64);
    if ((t & 63) == 0) ws[t >> 6] = sum;
    __syncthreads();
    if (t == 0) {
        const float tot = ws[0] + ws[1] + ws[2] + ws[3];
        out[0] = -tot / (float)((long long)B * C * H * W);
    }
}

extern "C" void kernel_launch(void* const* d_in, const int* in_sizes, int n_in,
                              void* d_out, int out_size, void* d_ws, size_t ws_size,
                              hipStream_t stream) {
    const float* y_pred = (const float*)d_in[0];
    const float* y_true = (const float*)d_in[1];
    float* out = (float*)d_out;
    float* partial = (float*)d_ws;  // NBLK floats = 8 KB

    ncc_partial<<<NBLK, TPB, 0, stream>>>(y_pred, y_true, partial);
    ncc_final<<<1, 256, 0, stream>>>(partial, out);
}